// Round 1
// baseline (5628.740 us; speedup 1.0000x reference)
//
#include <hip/hip_runtime.h>

typedef unsigned short u16;
typedef unsigned int u32;
typedef __bf16 bf16;
typedef bf16 bf16x8 __attribute__((ext_vector_type(8)));
typedef u16 u16x8 __attribute__((ext_vector_type(8)));
typedef float f32x4 __attribute__((ext_vector_type(4)));

#define DEV static __device__ __forceinline__

DEV u16 f2bf(float f) { return __builtin_bit_cast(u16, (bf16)f); }
DEV u32 pack2(float a, float b) { return (u32)f2bf(a) | ((u32)f2bf(b) << 16); }
DEV float bf2f(u16 u) { u32 v = ((u32)u) << 16; return __builtin_bit_cast(float, v); }
DEV bf16x8 frag_ld(const u16* p) { return __builtin_bit_cast(bf16x8, *(const u16x8*)p); }

#define MFMA(a, b, c) __builtin_amdgcn_mfma_f32_16x16x32_bf16(a, b, c, 0, 0, 0)

// ---------------------------------------------------------------- embed gather
__global__ __launch_bounds__(256) void embed_k(const int* __restrict__ tok,
                                               const float* __restrict__ E,
                                               float* __restrict__ Y) {
  int row = blockIdx.x, t = threadIdx.x;
  int tk = tok[row];
  *(float4*)&Y[(size_t)row * 1024 + t * 4] =
      *(const float4*)&E[(size_t)tk * 1024 + t * 4];
}

// ---------------------------------------------------------------- rmsnorm -> bf16
__global__ __launch_bounds__(256) void rmsnorm_k(const float* __restrict__ X,
                                                 const float* __restrict__ Sc,
                                                 u16* __restrict__ Out) {
  int row = blockIdx.x, t = threadIdx.x;
  const float4 xv = *(const float4*)&X[(size_t)row * 1024 + t * 4];
  float ss = xv.x * xv.x + xv.y * xv.y + xv.z * xv.z + xv.w * xv.w;
#pragma unroll
  for (int off = 32; off > 0; off >>= 1) ss += __shfl_down(ss, off);
  __shared__ float red[4];
  if ((t & 63) == 0) red[t >> 6] = ss;
  __syncthreads();
  float tot = red[0] + red[1] + red[2] + red[3];
  float r = rsqrtf(tot * (1.0f / 1024.0f) + 1e-6f);
  const float4 sv = *(const float4*)&Sc[t * 4];
  uint2 u;
  u.x = pack2(xv.x * r * sv.x, xv.y * r * sv.y);
  u.y = pack2(xv.z * r * sv.z, xv.w * r * sv.w);
  *(uint2*)&Out[(size_t)row * 1024 + t * 4] = u;
}

// ---------------------------------------------------------------- GEMM
// A bf16 [M][K], B fp32 [K][N] (converted to bf16 in staging), 128x128 tile, BK=32.
// EPI: 0 = write fp32, 1 = write bf16, 2 = fp32 +=, 3 = bf16 silu(G)*acc
template <int EPI>
__global__ __launch_bounds__(256) void gemm_k(
    const u16* __restrict__ A, const float* __restrict__ B0,
    const float* __restrict__ B1, const float* __restrict__ B2,
    void* __restrict__ C0, void* __restrict__ C1, void* __restrict__ C2,
    const float* __restrict__ Gaux, int M, int N, int K) {
  const float* B = B0;
  void* Cv = C0;
  if (blockIdx.z == 1) { B = B1; Cv = C1; }
  if (blockIdx.z == 2) { B = B2; Cv = C2; }
  const int m0 = blockIdx.y * 128, n0 = blockIdx.x * 128;
  __shared__ u16 As[128 * 40];  // [row][k], stride 40 pads banks (2-way only)
  __shared__ u16 Bs[128 * 40];  // [n][k] transposed, stride 40
  const int t = threadIdx.x;
  const int lane = t & 63, w = t >> 6;
  const int lr = lane & 15, lg = lane >> 4;
  const int wm = (w >> 1) * 64, wn = (w & 1) * 64;

  f32x4 acc[4][4];
#pragma unroll
  for (int i = 0; i < 4; ++i)
#pragma unroll
    for (int j = 0; j < 4; ++j) acc[i][j] = (f32x4){0.f, 0.f, 0.f, 0.f};

  int arow[2], aoff[2], bkp[2], bnq[2];
#pragma unroll
  for (int i = 0; i < 2; ++i) {
    int c = t + i * 256;
    arow[i] = c >> 2;
    aoff[i] = (c & 3) * 8;
    bkp[i] = c >> 5;
    bnq[i] = c & 31;
  }

  uint4 pa[2];
  float4 pb0[2], pb1[2];
#pragma unroll
  for (int i = 0; i < 2; ++i) {  // prefetch k0 = 0
    pa[i] = *(const uint4*)&A[(size_t)(m0 + arow[i]) * K + aoff[i]];
    const float* bp = B + (size_t)(2 * bkp[i]) * N + n0 + bnq[i] * 4;
    pb0[i] = *(const float4*)bp;
    pb1[i] = *(const float4*)(bp + N);
  }

  for (int k0 = 0; k0 < K; k0 += 32) {
    __syncthreads();
#pragma unroll
    for (int i = 0; i < 2; ++i) {
      *(uint4*)&As[arow[i] * 40 + aoff[i]] = pa[i];
      int nq = bnq[i], kp = bkp[i];
      *(u32*)&Bs[(nq * 4 + 0) * 40 + 2 * kp] = pack2(pb0[i].x, pb1[i].x);
      *(u32*)&Bs[(nq * 4 + 1) * 40 + 2 * kp] = pack2(pb0[i].y, pb1[i].y);
      *(u32*)&Bs[(nq * 4 + 2) * 40 + 2 * kp] = pack2(pb0[i].z, pb1[i].z);
      *(u32*)&Bs[(nq * 4 + 3) * 40 + 2 * kp] = pack2(pb0[i].w, pb1[i].w);
    }
    __syncthreads();
    if (k0 + 32 < K) {
      int kn = k0 + 32;
#pragma unroll
      for (int i = 0; i < 2; ++i) {
        pa[i] = *(const uint4*)&A[(size_t)(m0 + arow[i]) * K + kn + aoff[i]];
        const float* bp = B + (size_t)(kn + 2 * bkp[i]) * N + n0 + bnq[i] * 4;
        pb0[i] = *(const float4*)bp;
        pb1[i] = *(const float4*)(bp + N);
      }
    }
    bf16x8 af[4], bfv[4];
#pragma unroll
    for (int mi = 0; mi < 4; ++mi)
      af[mi] = frag_ld(&As[(wm + mi * 16 + lr) * 40 + lg * 8]);
#pragma unroll
    for (int ni = 0; ni < 4; ++ni)
      bfv[ni] = frag_ld(&Bs[(wn + ni * 16 + lr) * 40 + lg * 8]);
#pragma unroll
    for (int mi = 0; mi < 4; ++mi)
#pragma unroll
      for (int ni = 0; ni < 4; ++ni)
        acc[mi][ni] = MFMA(af[mi], bfv[ni], acc[mi][ni]);
  }

#pragma unroll
  for (int mi = 0; mi < 4; ++mi)
#pragma unroll
    for (int ni = 0; ni < 4; ++ni)
#pragma unroll
      for (int r = 0; r < 4; ++r) {
        int gm = m0 + wm + mi * 16 + lg * 4 + r;
        int gn = n0 + wn + ni * 16 + lr;
        size_t idx = (size_t)gm * N + gn;
        float v = acc[mi][ni][r];
        if (EPI == 0) ((float*)Cv)[idx] = v;
        else if (EPI == 1) ((u16*)Cv)[idx] = f2bf(v);
        else if (EPI == 2) ((float*)Cv)[idx] += v;
        else {
          float g = Gaux[idx];
          ((u16*)Cv)[idx] = f2bf((g / (1.f + __expf(-g))) * v);
        }
      }
}

// ---------------------------------------------------------------- RoPE (q scaled 1/8)
// in: [B][L][H][64] bf16; out: [B*H][L][64] bf16
__global__ __launch_bounds__(256) void rope_k(const u16* __restrict__ Qin,
                                              const u16* __restrict__ Kin,
                                              u16* __restrict__ Qo,
                                              u16* __restrict__ Ko) {
  int idx = blockIdx.x * 256 + threadIdx.x;  // B*L*H*32 = 1048576
  int i = idx & 31;
  int h = (idx >> 5) & 15;
  int l = (idx >> 9) & 1023;
  int b = idx >> 19;
  float inv_ts = exp2f((float)i * (-13.287712379549449f / 32.f));  // 10000^(-i/32)
  float ang = (float)l * inv_ts;
  float sn, cs;
  sincosf(ang, &sn, &cs);
  size_t ib = (((size_t)b * 1024 + l) * 16 + h) * 64 + i;
  size_t ob = (((size_t)b * 16 + h) * 1024 + l) * 64 + i;
  float qf = bf2f(Qin[ib]), qs = bf2f(Qin[ib + 32]);
  Qo[ob] = f2bf((qf * cs - qs * sn) * 0.125f);
  Qo[ob + 32] = f2bf((qs * cs + qf * sn) * 0.125f);
  float kf = bf2f(Kin[ib]), ks = bf2f(Kin[ib + 32]);
  Ko[ob] = f2bf(kf * cs - ks * sn);
  Ko[ob + 32] = f2bf(ks * cs + kf * sn);
}

// ---------------------------------------------------------------- V transpose
// in: [B][L][H][64]; out: [B*H][64][L]
__global__ __launch_bounds__(256) void vtrans_k(const u16* __restrict__ Vin,
                                                u16* __restrict__ Vt) {
  int lt = blockIdx.x, bh = blockIdx.y;
  int b = bh >> 4, h = bh & 15;
  __shared__ u16 tile[64 * 72];
  int t = threadIdx.x;
#pragma unroll
  for (int i = 0; i < 2; ++i) {
    int c = t + i * 256;
    int row = c >> 3, off = c & 7;
    *(uint4*)&tile[row * 72 + off * 8] =
        *(const uint4*)&Vin[(((size_t)b * 1024 + lt * 64 + row) * 16 + h) * 64 + off * 8];
  }
  __syncthreads();
#pragma unroll
  for (int i = 0; i < 2; ++i) {
    int c = t + i * 256;
    int d = c >> 3, off = c & 7;
    u16x8 vv;
#pragma unroll
    for (int j = 0; j < 8; ++j) vv[j] = tile[(off * 8 + j) * 72 + d];
    *(uint4*)&Vt[((size_t)bh * 64 + d) * 1024 + lt * 64 + off * 8] =
        __builtin_bit_cast(uint4, vv);
  }
}

// ---------------------------------------------------------------- flash attention
// Q,K: [B*H][L][64] bf16 (Q pre-scaled), V: [B*H][64][L] bf16 -> O: [B][L][H][64] bf16
__global__ __launch_bounds__(256) void attn_k(const u16* __restrict__ Q,
                                              const u16* __restrict__ Kg,
                                              const u16* __restrict__ Vg,
                                              u16* __restrict__ O) {
  const int L = 1024;
  int qt = blockIdx.x, bh = blockIdx.y;
  int b = bh >> 4, h = bh & 15;
  __shared__ u16 Ks[64 * 72];  // [key][dim]
  __shared__ u16 Vs[64 * 72];  // [dim][key]
  __shared__ u16 Ps[64 * 72];  // [q][key] bf16
  __shared__ float Ss[64 * 65];
  __shared__ float mS[64], lS[64], aS[64];
  int t = threadIdx.x, w = t >> 6, lane = t & 63, lr = lane & 15, lg = lane >> 4;

  int qrow = qt * 64 + w * 16 + lr;
  const u16* qp = Q + ((size_t)bh * L + qrow) * 64;
  bf16x8 qa0 = frag_ld(qp + lg * 8);
  bf16x8 qa1 = frag_ld(qp + 32 + lg * 8);

  f32x4 o[4];
#pragma unroll
  for (int i = 0; i < 4; ++i) o[i] = (f32x4){0.f, 0.f, 0.f, 0.f};
  if (t < 64) { mS[t] = -3.0e38f; lS[t] = 0.f; }

  for (int kt = 0; kt <= qt; ++kt) {
    __syncthreads();
#pragma unroll
    for (int i = 0; i < 2; ++i) {
      int c = t + i * 256;
      int row = c >> 3, off = c & 7;
      *(uint4*)&Ks[row * 72 + off * 8] =
          *(const uint4*)&Kg[((size_t)bh * L + kt * 64 + row) * 64 + off * 8];
      *(uint4*)&Vs[row * 72 + off * 8] =
          *(const uint4*)&Vg[((size_t)bh * 64 + row) * L + kt * 64 + off * 8];
    }
    __syncthreads();
    f32x4 s[4];
#pragma unroll
    for (int ni = 0; ni < 4; ++ni) {
      bf16x8 b0 = frag_ld(&Ks[(ni * 16 + lr) * 72 + lg * 8]);
      bf16x8 b1 = frag_ld(&Ks[(ni * 16 + lr) * 72 + 32 + lg * 8]);
      f32x4 a = (f32x4){0.f, 0.f, 0.f, 0.f};
      a = MFMA(qa0, b0, a);
      a = MFMA(qa1, b1, a);
      s[ni] = a;
    }
#pragma unroll
    for (int ni = 0; ni < 4; ++ni)
#pragma unroll
      for (int r = 0; r < 4; ++r)
        Ss[(w * 16 + lg * 4 + r) * 65 + ni * 16 + lr] = s[ni][r];
    __syncthreads();
    if (t < 64) {
      int nv = (kt == qt) ? (t + 1) : 64;  // causal mask within diagonal tile
      float mold = mS[t];
      float mx = mold;
      for (int j = 0; j < nv; ++j) mx = fmaxf(mx, Ss[t * 65 + j]);
      float alpha = __expf(mold - mx);
      float sum = 0.f;
      for (int j = 0; j < 64; ++j) {
        float p = (j < nv) ? __expf(Ss[t * 65 + j] - mx) : 0.f;
        sum += p;
        Ps[t * 72 + j] = f2bf(p);
      }
      mS[t] = mx;
      lS[t] = lS[t] * alpha + sum;
      aS[t] = alpha;
    }
    __syncthreads();
    float al[4];
#pragma unroll
    for (int r = 0; r < 4; ++r) al[r] = aS[w * 16 + lg * 4 + r];
#pragma unroll
    for (int ni = 0; ni < 4; ++ni)
#pragma unroll
      for (int r = 0; r < 4; ++r) o[ni][r] *= al[r];
    bf16x8 pa0 = frag_ld(&Ps[(w * 16 + lr) * 72 + lg * 8]);
    bf16x8 pa1 = frag_ld(&Ps[(w * 16 + lr) * 72 + 32 + lg * 8]);
#pragma unroll
    for (int ni = 0; ni < 4; ++ni) {
      bf16x8 v0 = frag_ld(&Vs[(ni * 16 + lr) * 72 + lg * 8]);
      bf16x8 v1 = frag_ld(&Vs[(ni * 16 + lr) * 72 + 32 + lg * 8]);
      o[ni] = MFMA(pa0, v0, o[ni]);
      o[ni] = MFMA(pa1, v1, o[ni]);
    }
  }
#pragma unroll
  for (int r = 0; r < 4; ++r) {
    float linv = 1.f / lS[w * 16 + lg * 4 + r];
    int ql = qt * 64 + w * 16 + lg * 4 + r;
#pragma unroll
    for (int ni = 0; ni < 4; ++ni)
      O[(((size_t)b * 1024 + ql) * 16 + h) * 64 + ni * 16 + lr] =
          f2bf(o[ni][r] * linv);
  }
}

// ---------------------------------------------------------------- launch
extern "C" void kernel_launch(void* const* d_in, const int* in_sizes, int n_in,
                              void* d_out, int out_size, void* d_ws, size_t ws_size,
                              hipStream_t stream) {
  const int* tokens = (const int*)d_in[0];
  const float* embed = (const float*)d_in[1];
  const float* ln1 = (const float*)d_in[2];
  const float* Wq = (const float*)d_in[3];
  const float* Wk = (const float*)d_in[4];
  const float* Wv = (const float*)d_in[5];
  const float* Wo = (const float*)d_in[6];
  const float* ln2 = (const float*)d_in[7];
  const float* Wg = (const float*)d_in[8];
  const float* Wp = (const float*)d_in[9];
  const float* Wd = (const float*)d_in[10];
  const float* out_ln = (const float*)d_in[11];
  const float* head = (const float*)d_in[12];
  float* outp = (float*)d_out;

  char* ws = (char*)d_ws;
  const size_t MB = 1ull << 20;
  float* y = (float*)(ws + 0 * MB);    // 8 MB  residual (fp32)
  u16* xb = (u16*)(ws + 8 * MB);       // 4 MB  normed acts (bf16)
  u16* qb = (u16*)(ws + 12 * MB);      // 4 MB
  u16* kb = (u16*)(ws + 16 * MB);      // 4 MB
  u16* vb = (u16*)(ws + 20 * MB);      // 4 MB
  u16* Qr = (u16*)(ws + 24 * MB);      // 4 MB
  u16* Kr = (u16*)(ws + 28 * MB);      // 4 MB
  u16* Vt = (u16*)(ws + 32 * MB);      // 4 MB
  u16* ao = (u16*)(ws + 36 * MB);      // 4 MB
  float* G = (float*)(ws + 40 * MB);   // 32 MB
  u16* hb = (u16*)(ws + 72 * MB);      // 16 MB (total 88 MB)

  dim3 blk(256);
  embed_k<<<2048, blk, 0, stream>>>(tokens, embed, y);
  for (int l = 0; l < 8; ++l) {
    const float* wq = Wq + (size_t)l * 1024 * 1024;
    const float* wk = Wk + (size_t)l * 1024 * 1024;
    const float* wv = Wv + (size_t)l * 1024 * 1024;
    const float* wo = Wo + (size_t)l * 1024 * 1024;
    const float* wg = Wg + (size_t)l * 1024 * 4096;
    const float* wp = Wp + (size_t)l * 1024 * 4096;
    const float* wd = Wd + (size_t)l * 4096 * 1024;

    rmsnorm_k<<<2048, blk, 0, stream>>>(y, ln1 + l * 1024, xb);
    gemm_k<1><<<dim3(8, 16, 3), blk, 0, stream>>>(xb, wq, wk, wv, qb, kb, vb,
                                                  nullptr, 2048, 1024, 1024);
    rope_k<<<4096, blk, 0, stream>>>(qb, kb, Qr, Kr);
    vtrans_k<<<dim3(16, 32), blk, 0, stream>>>(vb, Vt);
    attn_k<<<dim3(16, 32), blk, 0, stream>>>(Qr, Kr, Vt, ao);
    gemm_k<2><<<dim3(8, 16, 1), blk, 0, stream>>>(ao, wo, nullptr, nullptr, y,
                                                  nullptr, nullptr, nullptr,
                                                  2048, 1024, 1024);
    rmsnorm_k<<<2048, blk, 0, stream>>>(y, ln2 + l * 1024, xb);
    gemm_k<0><<<dim3(32, 16, 1), blk, 0, stream>>>(xb, wg, nullptr, nullptr, G,
                                                   nullptr, nullptr, nullptr,
                                                   2048, 4096, 1024);
    gemm_k<3><<<dim3(32, 16, 1), blk, 0, stream>>>(xb, wp, nullptr, nullptr, hb,
                                                   nullptr, nullptr, G,
                                                   2048, 4096, 1024);
    gemm_k<2><<<dim3(8, 16, 1), blk, 0, stream>>>(hb, wd, nullptr, nullptr, y,
                                                  nullptr, nullptr, nullptr,
                                                  2048, 1024, 4096);
  }
  rmsnorm_k<<<2048, blk, 0, stream>>>(y, out_ln, xb);
  gemm_k<0><<<dim3(250, 16, 1), blk, 0, stream>>>(xb, head, nullptr, nullptr,
                                                  outp, nullptr, nullptr, nullptr,
                                                  2048, 32000, 1024);
}